// Round 8
// baseline (187.756 us; speedup 1.0000x reference)
//
#include <hip/hip_runtime.h>
#include <math.h>

// Problem constants (B=1 hardcoded).
#define M_TOT 8192
#define NXY   192
#define NPIX  (192*192)   // 36864
#define NC    8
#define REC   20          // floats per packed record (fp32 fallback path)

// GEMM geometry: C[r=(y*8+c), n'=2x+{re,im}] = sum_k' A[r,k'] B[k',n']
//   A[r, 2m+{0,1}] = Re/Im( w[c,m] * Ey[m,y] )   (computed in-kernel, never stored)
//   BT[n'][k']: row 2x   = ( cos,-sin)(kx*gx) interleaved over k'=2m
//               row 2x+1 = ( sin, cos)(kx*gx)
#define GM 1536
#define GN 384
#define GK 16384
#define KSPLIT 16
#define KCHUNK (GK/KSPLIT)   // 1024 k' = 512 m
#define BK 64                // k' per LDS step (32 m)
#define NSTEP (KCHUNK/BK)    // 16
#define BM 96                // 12 y * 8 c
#define LDK 72               // padded LDS row stride (halves), 144B (16B mult)

typedef _Float16 fp16;
typedef fp16 f16x8 __attribute__((ext_vector_type(8)));
typedef float f32x4 __attribute__((ext_vector_type(4)));

#define INV2PI 0.15915494309189535f

// ---------------------------------------------------------------------------
// pack_W: W[c*8192+m] = (kr*dc, ki*dc)  (float2, 512 KB)
// ---------------------------------------------------------------------------
__global__ __launch_bounds__(256) void pack_W(
    const float* __restrict__ kr, const float* __restrict__ ki,
    const float* __restrict__ dc, float2* __restrict__ W)
{
    int i = blockIdx.x * 256 + threadIdx.x;   // 65536
    int m = i & 8191;
    float d = dc[m];
    W[i] = make_float2(kr[i] * d, ki[i] * d);
}

// ---------------------------------------------------------------------------
// pack_B: BT[n'=2x+e][k'=2m+g]  (fp16 row-major, k fastest) — proven round 7.
// ---------------------------------------------------------------------------
__global__ __launch_bounds__(256) void pack_B_mfma(
    const float* __restrict__ traj, fp16* __restrict__ BT)
{
    int tid = blockIdx.x * 256 + threadIdx.x;   // 192*8192
    int x = tid >> 13;
    int m = tid & 8191;
    float kx = traj[m];
    float gx = (float)(x - 96);
    float r  = __builtin_amdgcn_fractf(kx * gx * INV2PI);
    float s  = __builtin_amdgcn_sinf(r);
    float c  = __builtin_amdgcn_cosf(r);
    unsigned int* B2 = (unsigned int*)BT;
    union { fp16 h[2]; unsigned int u; } p0, p1;
    p0.h[0] = (fp16)c;  p0.h[1] = (fp16)(-s);   // row 2x:   (c, -s)
    p1.h[0] = (fp16)s;  p1.h[1] = (fp16)c;      // row 2x+1: (s,  c)
    B2[(size_t)x * GK + m]          = p0.u;
    B2[(size_t)x * GK + (GK/2) + m] = p1.u;
}

// ---------------------------------------------------------------------------
// gemm_fused: BM=96 x BN=384 (full N), A-tile computed in-kernel into LDS.
// grid = 256 (tm 0..15 x kz 0..15), 512 threads (8 waves, 2m x 4n).
// P (f16): [kz][GM][GN].
// ---------------------------------------------------------------------------
__global__ __launch_bounds__(512) void gemm_fused(
    const float2* __restrict__ W, const float* __restrict__ traj,
    const fp16* __restrict__ BT, fp16* __restrict__ P)
{
    __shared__ __align__(16) fp16 a_s[BM][LDK];
    __shared__ __align__(16) fp16 b_s[GN][LDK];

    const int bid = blockIdx.x;
    const int kz  = bid & 15;       // consecutive bids (round-robin XCDs) share kz per XCD
    const int tm  = bid >> 4;       // 0..15
    const int t   = threadIdx.x;

    // --- B staging mapping: 6 x 16B segments/thread/step
    const int brow0 = t >> 3;       // 0..63 (+ i*64)
    const int bseg  = t & 7;
    const fp16* pB = BT + (size_t)kz * KCHUNK + bseg * 8;

    // --- A producer mapping: threads t<384 -> (yl = t>>5 in 0..11, ml = t&31)
    const int yl = t >> 5;
    const int ml = t & 31;
    const bool aprod = (yl < 12);
    const float gy = (float)(tm * 12 + yl - 96);

    // --- MFMA mapping (identical conventions to the round-7 passing kernel)
    const int w_ = t >> 6, wm = w_ >> 2, wn = w_ & 3;   // 2m x 4n waves
    const int lane = t & 63, lr = lane & 15, lk = lane >> 4;

    f32x4 acc[3][6] = {};
    uint4 breg[6];

#define LOADB(ST)                                                          \
    _Pragma("unroll")                                                      \
    for (int i = 0; i < 6; ++i) {                                          \
        int rrow = i * 64 + brow0;                                         \
        breg[i] = *(const uint4*)(pB + (size_t)rrow * GK + (ST) * BK);     \
    }

    LOADB(0)

    for (int step = 0; step < NSTEP; ++step) {
        // ---- compute this step's A values (registers) ----
        unsigned int areg[NC];
        if (aprod) {
            int mg = kz * (KCHUNK/2) + step * (BK/2) + ml;   // global m
            float ky = traj[M_TOT + mg];
            float r  = __builtin_amdgcn_fractf(ky * gy * INV2PI);
            float sy = __builtin_amdgcn_sinf(r);
            float cy = __builtin_amdgcn_cosf(r);
#pragma unroll
            for (int c = 0; c < NC; ++c) {
                float2 wv = W[c * M_TOT + mg];
                union { fp16 h[2]; unsigned int u; } pk;
                pk.h[0] = (fp16)(wv.x * cy - wv.y * sy);   // Re(w*Ey)
                pk.h[1] = (fp16)(wv.x * sy + wv.y * cy);   // Im(w*Ey)
                areg[c] = pk.u;
            }
        }

        __syncthreads();            // previous step's LDS reads complete
#pragma unroll
        for (int i = 0; i < 6; ++i) {
            int rrow = i * 64 + brow0;
            *(uint4*)&b_s[rrow][bseg * 8] = breg[i];
        }
        if (aprod) {
#pragma unroll
            for (int c = 0; c < NC; ++c)
                *(unsigned int*)&a_s[yl * 8 + c][2 * ml] = areg[c];
        }
        __syncthreads();            // LDS tile visible

        if (step + 1 < NSTEP) { LOADB(step + 1) }   // prefetch overlaps MFMA

#pragma unroll
        for (int kk = 0; kk < 2; ++kk) {
            const int ko = kk * 32 + lk * 8;
            f16x8 af[3];
#pragma unroll
            for (int mi = 0; mi < 3; ++mi)
                af[mi] = *(const f16x8*)&a_s[wm * 48 + mi * 16 + lr][ko];
#pragma unroll
            for (int nj = 0; nj < 6; ++nj) {
                f16x8 bf = *(const f16x8*)&b_s[wn * 96 + nj * 16 + lr][ko];
#pragma unroll
                for (int mi = 0; mi < 3; ++mi)
                    acc[mi][nj] = __builtin_amdgcn_mfma_f32_16x16x32_f16(
                        af[mi], bf, acc[mi][nj], 0, 0, 0);
            }
        }
    }

    // ---- epilogue: f32 acc -> f16 partials (index math per round-7) ----
    fp16* Pz = P + (size_t)kz * GM * GN;
#pragma unroll
    for (int mi = 0; mi < 3; ++mi)
#pragma unroll
        for (int nj = 0; nj < 6; ++nj) {
            const int gcol = wn * 96 + nj * 16 + lr;
#pragma unroll
            for (int reg = 0; reg < 4; ++reg) {
                const int grow = tm * 96 + wm * 48 + mi * 16 + lk * 4 + reg;
                Pz[(size_t)grow * GN + gcol] = (fp16)acc[mi][nj][reg];
            }
        }
}

// ---------------------------------------------------------------------------
// combine2: reduce kz, coil-combine with conj(smaps), magnitude.
// 16x16 pixel tiles: thread -> x = x0 + (tid>>4), y = y0 + (tid&15):
// P reads 64B-line-efficient in x, smaps/out 64B-line-efficient in y.
// ---------------------------------------------------------------------------
__global__ __launch_bounds__(256) void combine2(
    const fp16* __restrict__ P,
    const float* __restrict__ smr, const float* __restrict__ smi,
    float* __restrict__ out)
{
    const int bid = blockIdx.x;                 // 144
    const int x = (bid % 12) * 16 + (threadIdx.x >> 4);
    const int y = (bid / 12) * 16 + (threadIdx.x & 15);
    const unsigned int* P32 = (const unsigned int*)P;   // half2 view

    float ore = 0.f, oim = 0.f;
#pragma unroll
    for (int c = 0; c < NC; ++c) {
        float re = 0.f, im = 0.f;
#pragma unroll
        for (int kz = 0; kz < KSPLIT; ++kz) {
            union { unsigned int u; fp16 h[2]; } v;
            v.u = P32[((size_t)kz * GM + y * 8 + c) * (GN/2) + x];
            re += (float)v.h[0];
            im += (float)v.h[1];
        }
        float sr = smr[c * NPIX + x * NXY + y];
        float si = smi[c * NPIX + x * NXY + y];
        ore += re * sr + im * si;               // * conj(smap)
        oim += im * sr - re * si;
    }
    out[x * NXY + y] = sqrtf(ore * ore + oim * oim);
}

// ===========================================================================
// fp32 fallback path (proven @328us) — used only if ws too small.
// ===========================================================================
__global__ __launch_bounds__(256) void pack_kernel(
    const float* __restrict__ kr, const float* __restrict__ ki,
    const float* __restrict__ traj, const float* __restrict__ dc,
    float* __restrict__ pack)
{
    int m = blockIdx.x * 256 + threadIdx.x;
    if (m >= M_TOT) return;
    float d = dc[m];
    float* r = pack + (size_t)m * REC;
#pragma unroll
    for (int c = 0; c < NC; ++c) {
        r[2*c]   = kr[c*M_TOT + m] * d;
        r[2*c+1] = ki[c*M_TOT + m] * d;
    }
    float ky = traj[M_TOT + m];
    r[16] = traj[m];
    r[17] = ky;
    r[18] = cosf(ky);
    r[19] = sinf(ky);
}

__global__ __launch_bounds__(256) void adj_main(
    const float* __restrict__ pack, float* __restrict__ partial, int mch)
{
    const int t = blockIdx.x * 256 + threadIdx.x;
    const int split = blockIdx.y;
    const int p0 = t * 2;
    const float gx  = (float)(p0 / NXY - NXY/2);
    const float gy0 = (float)(p0 % NXY - NXY/2);

    float2 par[NC], pai[NC];
#pragma unroll
    for (int c = 0; c < NC; ++c) {
        par[c] = make_float2(0.f, 0.f);
        pai[c] = make_float2(0.f, 0.f);
    }
    const float* rec = pack + (size_t)split * mch * REC;
    for (int m = 0; m < mch; ++m, rec += REC) {
        const float4* r4 = (const float4*)rec;
        float4 w01 = r4[0], w23 = r4[1], w45 = r4[2], w67 = r4[3], tkk = r4[4];
        float ph = fmaf(tkk.x, gx, tkk.y * gy0);
        float r  = __builtin_amdgcn_fractf(ph * INV2PI);
        float s0 = __builtin_amdgcn_sinf(r);
        float c0 = __builtin_amdgcn_cosf(r);
        float c1 = fmaf(c0, tkk.z, -(s0 * tkk.w));
        float s1 = fmaf(s0, tkk.z,  (c0 * tkk.w));
#define COIL(WR, WI, IDX)                                                \
        par[IDX].x = fmaf((WR), c0, fmaf(-(WI), s0, par[IDX].x));        \
        par[IDX].y = fmaf((WR), c1, fmaf(-(WI), s1, par[IDX].y));        \
        pai[IDX].x = fmaf((WR), s0, fmaf( (WI), c0, pai[IDX].x));        \
        pai[IDX].y = fmaf((WR), s1, fmaf( (WI), c1, pai[IDX].y));
        COIL(w01.x, w01.y, 0) COIL(w01.z, w01.w, 1)
        COIL(w23.x, w23.y, 2) COIL(w23.z, w23.w, 3)
        COIL(w45.x, w45.y, 4) COIL(w45.z, w45.w, 5)
        COIL(w67.x, w67.y, 6) COIL(w67.z, w67.w, 7)
#undef COIL
    }
#pragma unroll
    for (int c = 0; c < NC; ++c) {
        float4 v = make_float4(par[c].x, pai[c].x, par[c].y, pai[c].y);
        *(float4*)(partial + ((size_t)(split*NC + c)*NPIX + p0)*2) = v;
    }
}

__global__ __launch_bounds__(256) void combine_kernel(
    const float* __restrict__ partial,
    const float* __restrict__ smr, const float* __restrict__ smi,
    float* __restrict__ out, int nsplit)
{
    const int p = blockIdx.x * 256 + threadIdx.x;
    float cr[NC], ci[NC];
#pragma unroll
    for (int c = 0; c < NC; ++c) { cr[c] = 0.f; ci[c] = 0.f; }
    for (int s = 0; s < nsplit; ++s)
#pragma unroll
        for (int c = 0; c < NC; ++c) {
            float2 v = *(const float2*)(partial + ((size_t)(s*NC + c)*NPIX + p)*2);
            cr[c] += v.x; ci[c] += v.y;
        }
    float re = 0.f, im = 0.f;
#pragma unroll
    for (int c = 0; c < NC; ++c) {
        float sr = smr[c*NPIX + p];
        float si = smi[c*NPIX + p];
        re += cr[c]*sr + ci[c]*si;
        im += ci[c]*sr - cr[c]*si;
    }
    out[p] = sqrtf(re*re + im*im);
}

__global__ __launch_bounds__(256) void adj_fallback(
    const float* __restrict__ kr, const float* __restrict__ ki,
    const float* __restrict__ traj, const float* __restrict__ dc,
    const float* __restrict__ smr, const float* __restrict__ smi,
    float* __restrict__ out)
{
    const int p = blockIdx.x * 256 + threadIdx.x;
    const float gx = (float)(p / NXY - NXY/2);
    const float gy = (float)(p % NXY - NXY/2);
    float ar[NC], ai[NC];
#pragma unroll
    for (int c = 0; c < NC; ++c) { ar[c] = 0.f; ai[c] = 0.f; }
    for (int m = 0; m < M_TOT; ++m) {
        float kx = traj[m];
        float ky = traj[M_TOT + m];
        float d  = dc[m];
        float ph = fmaf(kx, gx, ky * gy);
        float r  = __builtin_amdgcn_fractf(ph * INV2PI);
        float s = __builtin_amdgcn_sinf(r);
        float c = __builtin_amdgcn_cosf(r);
#pragma unroll
        for (int cc = 0; cc < NC; ++cc) {
            float wr = kr[cc*M_TOT + m] * d;
            float wi = ki[cc*M_TOT + m] * d;
            ar[cc] = fmaf(wr, c, fmaf(-wi, s, ar[cc]));
            ai[cc] = fmaf(wr, s, fmaf( wi, c, ai[cc]));
        }
    }
    float re = 0.f, im = 0.f;
#pragma unroll
    for (int c = 0; c < NC; ++c) {
        float sr = smr[c*NPIX + p];
        float si = smi[c*NPIX + p];
        re += ar[c]*sr + ai[c]*si;
        im += ai[c]*sr - ar[c]*si;
    }
    out[p] = sqrtf(re*re + im*im);
}

// ---------------------------------------------------------------------------
extern "C" void kernel_launch(void* const* d_in, const int* in_sizes, int n_in,
                              void* d_out, int out_size, void* d_ws, size_t ws_size,
                              hipStream_t stream)
{
    const float* kr   = (const float*)d_in[0];
    const float* ki   = (const float*)d_in[1];
    const float* traj = (const float*)d_in[2];
    const float* smr  = (const float*)d_in[3];
    const float* smi  = (const float*)d_in[4];
    const float* dc   = (const float*)d_in[5];
    float* out = (float*)d_out;

    const size_t B_bytes = (size_t)GN * GK * sizeof(fp16);            // 12.58 MB
    const size_t P_bytes = (size_t)KSPLIT * GM * GN * sizeof(fp16);   // 18.87 MB
    const size_t W_bytes = (size_t)NC * M_TOT * sizeof(float2);       // 0.5 MB
    const size_t need_mfma = B_bytes + P_bytes + W_bytes;             // ~32 MB

    if (ws_size >= need_mfma) {
        fp16*   BT = (fp16*)d_ws;
        fp16*   P  = (fp16*)((char*)d_ws + B_bytes);
        float2* W  = (float2*)((char*)d_ws + B_bytes + P_bytes);
        pack_W<<<(NC*M_TOT)/256, 256, 0, stream>>>(kr, ki, dc, W);
        pack_B_mfma<<<(NXY*M_TOT)/256, 256, 0, stream>>>(traj, BT);
        gemm_fused<<<KSPLIT*(GM/BM/NC*8)/ /* =16*16 */ 1, 512, 0, stream>>>(W, traj, BT, P);
        combine2<<<NPIX/256, 256, 0, stream>>>(P, smr, smi, out);
        return;
    }

    const size_t pack_bytes = (size_t)M_TOT * REC * sizeof(float);
    int split = 0;
    for (int s = 32; s >= 8; s >>= 1) {
        size_t need = pack_bytes + (size_t)s * NC * NPIX * 2 * sizeof(float);
        if (ws_size >= need) { split = s; break; }
    }
    if (split > 0) {
        float* pack    = (float*)d_ws;
        float* partial = pack + (size_t)M_TOT * REC;
        int mch = M_TOT / split;
        pack_kernel<<<(M_TOT + 255)/256, 256, 0, stream>>>(kr, ki, traj, dc, pack);
        adj_main<<<dim3(NPIX/2/256, split), 256, 0, stream>>>(pack, partial, mch);
        combine_kernel<<<NPIX/256, 256, 0, stream>>>(partial, smr, smi, out, split);
    } else {
        adj_fallback<<<NPIX/256, 256, 0, stream>>>(kr, ki, traj, dc, smr, smi, out);
    }
}